// Round 14
// baseline (193.167 us; speedup 1.0000x reference)
//
#include <hip/hip_runtime.h>
#include <hip/hip_bf16.h>

using bf16 = __hip_bfloat16;
typedef __attribute__((ext_vector_type(8))) short short8;
typedef __attribute__((ext_vector_type(4))) float floatx4;
typedef __attribute__((ext_vector_type(16))) float floatx16;

#define MFMA_BF16(a, b, c) __builtin_amdgcn_mfma_f32_16x16x32_bf16((a), (b), (c), 0, 0, 0)
#define MFMA32(a, b, c) __builtin_amdgcn_mfma_f32_32x32x16_bf16((a), (b), (c), 0, 0, 0)

__device__ __forceinline__ void gload_lds16(const bf16* g, bf16* l) {
  __builtin_amdgcn_global_load_lds((__attribute__((address_space(1))) void*)g,
                                   (__attribute__((address_space(3))) void*)l,
                                   16, 0, 0);
}

__device__ __forceinline__ unsigned short bfbits(float f) {
  bf16 b = __float2bfloat16(f);
  return *reinterpret_cast<unsigned short*>(&b);
}

// K-scale: SCALE * log2(e) folded so flash uses raw v_exp_f32 (=exp2)
#define KSCALE 0.18033688011112042f

// ---------- fused prep: dtype probe + cvt x + weight transposes + mask cvt ------
// grid 8193. EVERY block computes isbf locally from the mask words (first 4KB,
// L2-cached; words are {0,0x3F800000} iff fp32). Blocks <4096: cvt x (fp32
// path). 4096..8191: 32x32 transpose tiles of w_qkv/w_out. Block 8192: writes
// flag + maskb for the gemms.
__global__ __launch_bounds__(256)
void prep_k(const void* __restrict__ msrc, bf16* __restrict__ maskb,
            int* __restrict__ flag,
            const void* __restrict__ xsrc, bf16* __restrict__ xb,
            const void* __restrict__ in0, bf16* __restrict__ out0,
            const void* __restrict__ in1, bf16* __restrict__ out1) {
  __shared__ int any;
  __shared__ bf16 tile[32][33];
  const int tid = threadIdx.x;
  if (tid == 0) any = 0;
  __syncthreads();
  const unsigned* mw = (const unsigned*)msrc;
  int bad = 0;
#pragma unroll
  for (int i = 0; i < 4; i++) {
    unsigned w_ = mw[tid * 4 + i];
    if (w_ != 0u && w_ != 0x3F800000u) bad = 1;
  }
  if (bad) atomicOr(&any, 1);
  __syncthreads();
  const int isbf = any;  // 1 => inputs bf16, 0 => fp32

  if (blockIdx.x == 8192) {  // flag + maskb producer
    if (tid == 0) flag[0] = isbf;
    if (isbf) {
#pragma unroll
      for (int i = 0; i < 2; i++)
        ((int4*)maskb)[tid * 2 + i] = ((const int4*)msrc)[tid * 2 + i];
    } else {
#pragma unroll
      for (int i = 0; i < 4; i++) {
        float4 v = ((const float4*)msrc)[tid * 4 + i];
        int o = tid * 16 + i * 4;
        maskb[o + 0] = __float2bfloat16(v.x);
        maskb[o + 1] = __float2bfloat16(v.y);
        maskb[o + 2] = __float2bfloat16(v.z);
        maskb[o + 3] = __float2bfloat16(v.w);
      }
    }
    return;
  }

  if (blockIdx.x < 4096) {  // x cvt (fp32 path only; bf16 path reads x directly)
    if (isbf) return;
    int i = (blockIdx.x * 256 + tid) * 4;
    float4 v = ((const float4*)xsrc)[i >> 2];
    xb[i + 0] = __float2bfloat16(v.x);
    xb[i + 1] = __float2bfloat16(v.y);
    xb[i + 2] = __float2bfloat16(v.z);
    xb[i + 3] = __float2bfloat16(v.w);
    return;
  }

  constexpr int R = 1024;
  const int t = blockIdx.x - 4096;
  const int bxi = t & 127;       // original transpose blockIdx.x
  const int by = (t >> 7) * 32;  // original blockIdx.y*32
  const void* in;
  bf16* out;
  int C, bx;
  if (bxi < 96) { in = in0; out = out0; C = 3072; bx = bxi * 32; }
  else          { in = in1; out = out1; C = 1024; bx = (bxi - 96) * 32; }
  int tx = tid & 31, ty = tid >> 5;
#pragma unroll
  for (int i = 0; i < 4; i++) {
    size_t idx = (size_t)(by + ty + i * 8) * C + bx + tx;
    tile[ty + i * 8][tx] =
        isbf ? ((const bf16*)in)[idx] : __float2bfloat16(((const float*)in)[idx]);
  }
  __syncthreads();
#pragma unroll
  for (int i = 0; i < 4; i++)
    out[(size_t)(bx + ty + i * 8) * R + by + tx] = tile[tx][ty + i * 8];
}

// ---------------- GEMM: C[M,N] = A[M,1024] @ Bt[N,1024]^T ----------------
// 128xNT tiles, BK=64 (two verbatim 128x32 halves per barrier pair). NT is a
// template param: MODE0 uses NT=192 -> grid 16x32 = 512 blocks = EXACTLY one
// scheduling round at 2 blocks/CU (vs 768 blocks = 1.5 rounds with a half-
// empty tail at NT=128), and 24 MFMAs/wave per K-half (better MFMA:barrier
// ratio). LDS 16+NT*64*2/1024 KB = 40KB @NT=192 (2 blocks/CU fit, 80<=160).
// Sections are 1024-aligned and fragment col-groups 16-aligned, so the
// per-element scatter logic is unaffected by 192-wide tiles straddling the
// Q/K/V boundaries. MODE 1 keeps NT=128 (N=1024).
// MODE 0: A = x [4096,1024], N=3072; scatters Q->[b,h,n,d], K and V in
// FRAGMENT-PACKED layouts (flash_k reads each MFMA fragment as one
// wave-contiguous 1KB load): packed elem (t=key>>6, half, c, gh, l31, j) at
// t*4096 + half*2048 + c*512 + gh*256 + l31*8 + j.
//   K: half=kt=(key>>5)&1, l31=key&31, d=(c*2+gh)*8+j  (pre-scaled KSCALE*mask)
//   V: half=dt=d>>5,       l31=d&31,   key_local=(c*2+gh)*8+j
// MODE 1: A = AO [4096,1024] (linear), N=1024 -> Co (bf16/f32 per flag).
// XCD-aware bijective swizzle (T1): nwg = 512 / 256, both % 8 == 0.
template <int MODE, int NT>
__global__ __launch_bounds__(256, 2)
void gemm_k(const bf16* __restrict__ A, const bf16* __restrict__ Aalt,
            const bf16* __restrict__ Bt,
            bf16* __restrict__ Qo, bf16* __restrict__ Ko, bf16* __restrict__ Vo,
            void* __restrict__ Co, const bf16* __restrict__ Mk,
            const int* __restrict__ flag) {
  constexpr int K = 1024;
  constexpr int NF = NT / 32;       // B fragments per wave (wave n-tile = NT/2)
  constexpr int BH = NT * 32;       // Bs elems per 32-col K-half
  __shared__ __align__(16) bf16 As[128 * 64];  // two 128x32 halves (0 / +4096)
  __shared__ __align__(16) bf16 Bs[NT * 64];   // two NTx32 halves (0 / +BH)

  const int tid = threadIdx.x;
  const int lane = tid & 63;
  const int wv = tid >> 6;
  const int wm = wv & 1, wn = wv >> 1;
  const int l15 = lane & 15, quad = lane >> 4;

  const int nbx = gridDim.x;
  const int nwg = nbx * gridDim.y;
  int wid = blockIdx.y * nbx + blockIdx.x;
  wid = (wid & 7) * (nwg >> 3) + (wid >> 3);
  const int bm = (wid / nbx) * 128;
  const int bn = (wid % nbx) * NT;

  const int sml = tid >> 2;
  const int sg = (tid & 3) ^ ((sml >> 1) & 3);

  const int isbf = *flag;
  const bf16* Ab = (MODE == 0 && isbf) ? Aalt : A;

  floatx4 acc[4][NF] = {};

  for (int k0 = 0; k0 < K; k0 += 64) {
    __syncthreads();
#pragma unroll
    for (int hf = 0; hf < 2; hf++) {
      const bf16* a0 = Ab + (size_t)(bm + sml) * K + k0 + hf * 32 + sg * 8;
      gload_lds16(a0, &As[hf * 4096 + tid * 8]);
      gload_lds16(a0 + (size_t)64 * K, &As[hf * 4096 + 2048 + tid * 8]);
      const bf16* b0 = Bt + (size_t)(bn + sml) * K + k0 + hf * 32 + sg * 8;
#pragma unroll
      for (int rg3 = 0; rg3 < NT / 64; rg3++)
        gload_lds16(b0 + (size_t)(rg3 * 64) * K, &Bs[hf * BH + rg3 * 2048 + tid * 8]);
    }
    __syncthreads();

#pragma unroll
    for (int hf = 0; hf < 2; hf++) {
      const bf16* Ah = &As[hf * 4096];
      const bf16* Bh = &Bs[hf * BH];
      short8 af[4], bfr[NF];
#pragma unroll
      for (int mi = 0; mi < 4; mi++) {
        int m = wm * 64 + mi * 16 + l15;
        af[mi] = *(const short8*)&Ah[m * 32 + ((quad ^ ((m >> 1) & 3)) * 8)];
      }
#pragma unroll
      for (int ni = 0; ni < NF; ni++) {
        int n = wn * (NT / 2) + ni * 16 + l15;
        bfr[ni] = *(const short8*)&Bh[n * 32 + ((quad ^ ((n >> 1) & 3)) * 8)];
      }
#pragma unroll
      for (int mi = 0; mi < 4; mi++)
#pragma unroll
        for (int ni = 0; ni < NF; ni++)
          acc[mi][ni] = MFMA_BF16(af[mi], bfr[ni], acc[mi][ni]);
    }
  }

#pragma unroll
  for (int mi = 0; mi < 4; mi++) {
    const int row0 = bm + wm * 64 + mi * 16 + quad * 4;
#pragma unroll
    for (int ni = 0; ni < NF; ni++) {
      const int col = bn + wn * (NT / 2) + ni * 16 + l15;
      if (MODE == 0) {
        const int sec = col >> 10;
        const int cc = col & 1023;
        const int h = cc >> 6, d = cc & 63;
        const int b_idx = row0 >> 11;
        const int nn0 = row0 & 2047;
        if (sec == 0) {
          bf16* dst = Qo + (size_t)(b_idx * 16 + h) * 131072 + (size_t)nn0 * 64 + d;
#pragma unroll
          for (int r = 0; r < 4; r++) dst[r * 64] = __float2bfloat16(acc[mi][ni][r]);
        } else if (sec == 1) {
          // fold SCALE*log2e*mask_j into K rows; packed-fragment K layout.
          const bf16* mrow = Mk + (size_t)b_idx * 2048 + nn0;
          const int t = nn0 >> 6, kt = (nn0 >> 5) & 1, l31r = nn0 & 31;
          const int g = d >> 3, j = d & 7;
          bf16* dst = Ko + (size_t)(b_idx * 16 + h) * 131072 + t * 4096 + kt * 2048 +
                      (g >> 1) * 512 + (g & 1) * 256 + l31r * 8 + j;
#pragma unroll
          for (int r = 0; r < 4; r++)
            dst[r * 8] = __float2bfloat16(acc[mi][ni][r] * KSCALE *
                                          __bfloat162float(mrow[r]));
        } else {
          // packed-fragment V layout. key = nn0 + r: j = (nn0&7)+r.
          const int t = nn0 >> 6;
          const int kl = nn0 & 63;
          const int g = kl >> 3, j0 = kl & 7;
          bf16* dst = Vo + (size_t)(b_idx * 16 + h) * 131072 + t * 4096 +
                      (d >> 5) * 2048 + (g >> 1) * 512 + (g & 1) * 256 + (d & 31) * 8 + j0;
          ushort4 u;
          u.x = bfbits(acc[mi][ni][0]);
          u.y = bfbits(acc[mi][ni][1]);
          u.z = bfbits(acc[mi][ni][2]);
          u.w = bfbits(acc[mi][ni][3]);
          *(ushort4*)dst = u;
        }
      } else {
        if (isbf) {
          bf16* C2 = (bf16*)Co;
#pragma unroll
          for (int r = 0; r < 4; r++)
            C2[(size_t)(row0 + r) * 1024 + col] = __float2bfloat16(acc[mi][ni][r]);
        } else {
          float* C2 = (float*)Co;
#pragma unroll
          for (int r = 0; r < 4; r++)
            C2[(size_t)(row0 + r) * 1024 + col] = acc[mi][ni][r];
        }
      }
    }
  }
}

// ---------------- flash attention v15 (r9/r10/r13 verbatim: ~48.4us, stable) ----
// Accepted floor for this structure after 9 variants (48.3-56us across staging/
// pipelining/waves/stagger axes). 4 waves/SIMD, direct-L2 fragment-packed KV,
// KV-split halves, no main-loop barriers; exp2 to fresh scalars; deferred rsum.
__global__ __launch_bounds__(512, 4)
void flash_k(const bf16* __restrict__ Q, const bf16* __restrict__ Kp,
             const bf16* __restrict__ Vp, bf16* __restrict__ AO) {
  __shared__ __align__(16) float cb[4 * 64 * 32];  // 32 KB combine buffer
  __shared__ float rbuf[4 * 64];                   // 1 KB rsum combine

  const int tid = threadIdx.x;
  const int lane = tid & 63;
  const int l31 = lane & 31;
  const int l5h = lane >> 5;  // 0..1
  const int w = tid >> 6;     // 0..7
  const int rg = w & 3;       // row group (32 rows each)
  const int half = w >> 2;    // KV half: 0 -> keys 0..1023, 1 -> 1024..2047

  // XCD-aware swizzle (bijective, 512 % 8 == 0)
  const int bid = blockIdx.x;
  const int wk = (bid & 7) * 64 + (bid >> 3);
  const int qt = wk & 15;  // 16 tiles x 128 rows
  const int hl = wk >> 4;  // b*16+h
  const int b_idx = hl >> 4, h = hl & 15;

  const bf16* Qh = Q + (size_t)hl * 131072;
  const int lo = l5h * 256 + l31 * 8;  // per-lane elem offset inside a fragment
  const bf16* kptr = Kp + (size_t)hl * 131072 + (size_t)(half * 16) * 4096 + lo;
  const bf16* vptr = Vp + (size_t)hl * 131072 + (size_t)(half * 16) * 4096 + lo;

  const int qbase = qt * 128 + rg * 32;
  const int qrow = qbase + l31;

  // Q fragments (B-operand of S^T): B[k=d][n=row]: lane n=l31, k=c*16+l5h*8+j
  short8 qf[4];
#pragma unroll
  for (int c = 0; c < 4; c++)
    qf[c] = *(const short8*)&Qh[(size_t)qrow * 64 + c * 16 + l5h * 8];

  floatx16 o_acc[2] = {};  // O^T: col=l31=row, d = dt*32 + (reg&3)+8*(reg>>2)+4*l5h
  float rsm0 = 0.f, rsm1 = 0.f, rsm2 = 0.f, rsm3 = 0.f;  // lane-local partials

  // preload K fragments of 32-key tile 0 (K packed: 32-key subtile stride 2048)
  short8 kf[4];
#pragma unroll
  for (int c = 0; c < 4; c++) kf[c] = *(const short8*)(kptr + c * 512);

#pragma unroll 1
  for (int it = 0; it < 32; ++it) {
    const int kv = it & 1;  // which 32-key half of the 64-key packed tile

    // S^T = K' Q^T : A = K'[key][d]: lane row=key=l31, k=l5h*8+j per c-chunk
    floatx16 s = {};
    __builtin_amdgcn_s_setprio(1);
#pragma unroll
    for (int c = 0; c < 4; c++) s = MFMA32(kf[c], qf[c], s);
    __builtin_amdgcn_s_setprio(0);

    // V loads for this tile, issued FIRST (in-order vmcnt => PV's wait doesn't
    // drain the K prefetch behind them)
    short8 vf[4];
#pragma unroll
    for (int dt = 0; dt < 2; dt++)
#pragma unroll
      for (int ch = 0; ch < 2; ch++)
        vf[dt * 2 + ch] = *(const short8*)(vptr + dt * 2048 + (kv * 2 + ch) * 512);

    // prefetch K fragments of next tile (kf dead after S-MFMAs)
    kptr += (it < 31) ? 2048 : 0;
#pragma unroll
    for (int c = 0; c < 4; c++) kf[c] = *(const short8*)(kptr + c * 512);

    // p = exp2(s) into FRESH scalars (no write-back into the AGPR-resident s)
    float e[16];
#pragma unroll
    for (int r = 0; r < 16; r += 4) {
      e[r + 0] = __builtin_amdgcn_exp2f(s[r + 0]);
      e[r + 1] = __builtin_amdgcn_exp2f(s[r + 1]);
      e[r + 2] = __builtin_amdgcn_exp2f(s[r + 2]);
      e[r + 3] = __builtin_amdgcn_exp2f(s[r + 3]);
      rsm0 += e[r + 0];
      rsm1 += e[r + 1];
      rsm2 += e[r + 2];
      rsm3 += e[r + 3];
    }

    // pf[ch][j] = P[key=ch*16+l5h*8+j][row=l31], built in-register (T12).
    short8 pf[2];
#pragma unroll
    for (int ch = 0; ch < 2; ch++) {
      const int rb = ch * 8;
      unsigned x0, x1, y0, y1;
      asm("v_cvt_pk_bf16_f32 %0, %1, %2" : "=v"(x0) : "v"(e[rb + 0]), "v"(e[rb + 1]));
      asm("v_cvt_pk_bf16_f32 %0, %1, %2" : "=v"(x1) : "v"(e[rb + 2]), "v"(e[rb + 3]));
      asm("v_cvt_pk_bf16_f32 %0, %1, %2" : "=v"(y0) : "v"(e[rb + 4]), "v"(e[rb + 5]));
      asm("v_cvt_pk_bf16_f32 %0, %1, %2" : "=v"(y1) : "v"(e[rb + 6]), "v"(e[rb + 7]));
      asm("v_permlane32_swap_b32 %0, %1" : "+v"(x0), "+v"(y0));
      asm("v_permlane32_swap_b32 %0, %1" : "+v"(x1), "+v"(y1));
      union { unsigned u[4]; short8 v; } cv;
      cv.u[0] = x0; cv.u[1] = x1; cv.u[2] = y0; cv.u[3] = y1;
      pf[ch] = cv.v;
    }

    // O^T += V^T P^T : A = V^T[d][key]: lane row=d=dt*32+l31 (per dt)
    __builtin_amdgcn_s_setprio(1);
#pragma unroll
    for (int dt = 0; dt < 2; dt++)
#pragma unroll
      for (int ch = 0; ch < 2; ch++)
        o_acc[dt] = MFMA32(vf[dt * 2 + ch], pf[ch], o_acc[dt]);
    __builtin_amdgcn_s_setprio(0);

    vptr += kv ? 4096 : 0;  // V packed-tile (64-key) stride, advance every 2 iters
  }

  // deferred rsum: one cross-half-of-wave shfl for this wave's 1024 keys
  float rsum = (rsm0 + rsm1) + (rsm2 + rsm3);
  rsum += __shfl_xor(rsum, 32, 64);

  // ---- combine KV halves: waves 4-7 hand o_acc/rsum to partner via LDS ----
  if (w >= 4) {
    const int slot = (w - 4) * 64 + lane;
    float4* dst = (float4*)(cb + (size_t)slot * 32);
#pragma unroll
    for (int dt = 0; dt < 2; dt++)
#pragma unroll
      for (int q = 0; q < 4; q++) {
        float4 v = make_float4(o_acc[dt][q * 4 + 0], o_acc[dt][q * 4 + 1],
                               o_acc[dt][q * 4 + 2], o_acc[dt][q * 4 + 3]);
        dst[(dt * 4 + q) ^ (lane & 7)] = v;  // xor-swizzle: conflict-free
      }
    rbuf[slot] = rsum;
  }
  __syncthreads();
  if (w < 4) {
    const int slot = w * 64 + lane;
    const float4* src = (const float4*)(cb + (size_t)slot * 32);
#pragma unroll
    for (int dt = 0; dt < 2; dt++)
#pragma unroll
      for (int q = 0; q < 4; q++) {
        float4 v = src[(dt * 4 + q) ^ (lane & 7)];
        o_acc[dt][q * 4 + 0] += v.x;
        o_acc[dt][q * 4 + 1] += v.y;
        o_acc[dt][q * 4 + 2] += v.z;
        o_acc[dt][q * 4 + 3] += v.w;
      }
    rsum += rbuf[slot];

    // epilogue: lane owns q-row qbase+l31; AO linear [b*2048+n][1024], col=h*64+d
    const float rinv = 1.f / rsum;
    bf16* orow = AO + (size_t)(b_idx * 2048 + qbase + l31) * 1024 + h * 64;
#pragma unroll
    for (int dt = 0; dt < 2; dt++)
#pragma unroll
      for (int rg2 = 0; rg2 < 4; rg2++) {
        ushort4 u;
        u.x = bfbits(o_acc[dt][rg2 * 4 + 0] * rinv);
        u.y = bfbits(o_acc[dt][rg2 * 4 + 1] * rinv);
        u.z = bfbits(o_acc[dt][rg2 * 4 + 2] * rinv);
        u.w = bfbits(o_acc[dt][rg2 * 4 + 3] * rinv);
        *(ushort4*)&orow[dt * 32 + rg2 * 8 + l5h * 4] = u;
      }
  }
}

extern "C" void kernel_launch(void* const* d_in, const int* in_sizes, int n_in,
                              void* d_out, int out_size, void* d_ws, size_t ws_size,
                              hipStream_t stream) {
  const void* x     = d_in[0];  // [2,2048,1024]  bf16 or fp32 (probed)
  const void* mask  = d_in[1];  // [2,2048]
  const void* w_qkv = d_in[2];  // [1024,3072]
  const void* w_out = d_in[3];  // [1024,1024]

  bf16* ws    = (bf16*)d_ws;
  bf16* xb    = ws;                     // 4194304 (fp32 path only; dead after gemm1)
  bf16* AO    = ws;                     // alias of xb, linear [4096,1024]
  bf16* wqkvT = ws + 4194304;           // 3145728
  bf16* woutT = wqkvT + 3145728;        // 1048576
  bf16* Qb    = woutT + 1048576;        // 4194304
  bf16* Kp    = Qb + 4194304;           // 4194304 (fragment-packed K)
  bf16* maskb = Kp + 4194304;           // 4096
  int*  flag  = (int*)(maskb + 4096);
  bf16* Vp    = (bf16*)d_out;           // 4194304 packed V (dead before gemm2 writes)

  prep_k<<<8193, 256, 0, stream>>>(mask, maskb, flag, x, xb, w_qkv, wqkvT,
                                   w_out, woutT);
  gemm_k<0, 192><<<dim3(16, 32), 256, 0, stream>>>(xb, (const bf16*)x, wqkvT, Qb,
                                                   Kp, Vp, nullptr, maskb, flag);
  flash_k<<<512, 512, 0, stream>>>(Qb, Kp, Vp, AO);
  gemm_k<1, 128><<<dim3(8, 32), 256, 0, stream>>>(AO, nullptr, woutT, nullptr,
                                                  nullptr, nullptr, d_out, nullptr,
                                                  flag);
}

// Round 16
// 183.512 us; speedup vs baseline: 1.0526x; 1.0526x over previous
//
#include <hip/hip_runtime.h>
#include <hip/hip_bf16.h>

using bf16 = __hip_bfloat16;
typedef __attribute__((ext_vector_type(8))) short short8;
typedef __attribute__((ext_vector_type(4))) float floatx4;
typedef __attribute__((ext_vector_type(16))) float floatx16;

#define MFMA_BF16(a, b, c) __builtin_amdgcn_mfma_f32_16x16x32_bf16((a), (b), (c), 0, 0, 0)
#define MFMA32(a, b, c) __builtin_amdgcn_mfma_f32_32x32x16_bf16((a), (b), (c), 0, 0, 0)

__device__ __forceinline__ void gload_lds16(const bf16* g, bf16* l) {
  __builtin_amdgcn_global_load_lds((__attribute__((address_space(1))) void*)g,
                                   (__attribute__((address_space(3))) void*)l,
                                   16, 0, 0);
}

__device__ __forceinline__ unsigned short bfbits(float f) {
  bf16 b = __float2bfloat16(f);
  return *reinterpret_cast<unsigned short*>(&b);
}

// K-scale: SCALE * log2(e) folded so flash uses raw v_exp_f32 (=exp2)
#define KSCALE 0.18033688011112042f

// ---------- fused prep: dtype probe + cvt x + weight transposes + mask cvt ------
// grid 8193. EVERY block computes isbf locally from the mask words (first 4KB,
// L2-cached; words are {0,0x3F800000} iff fp32). Blocks <4096: cvt x (fp32
// path). 4096..8191: 32x32 transpose tiles of w_qkv/w_out. Block 8192: writes
// flag + maskb for the gemms.
__global__ __launch_bounds__(256)
void prep_k(const void* __restrict__ msrc, bf16* __restrict__ maskb,
            int* __restrict__ flag,
            const void* __restrict__ xsrc, bf16* __restrict__ xb,
            const void* __restrict__ in0, bf16* __restrict__ out0,
            const void* __restrict__ in1, bf16* __restrict__ out1) {
  __shared__ int any;
  __shared__ bf16 tile[32][33];
  const int tid = threadIdx.x;
  if (tid == 0) any = 0;
  __syncthreads();
  const unsigned* mw = (const unsigned*)msrc;
  int bad = 0;
#pragma unroll
  for (int i = 0; i < 4; i++) {
    unsigned w_ = mw[tid * 4 + i];
    if (w_ != 0u && w_ != 0x3F800000u) bad = 1;
  }
  if (bad) atomicOr(&any, 1);
  __syncthreads();
  const int isbf = any;  // 1 => inputs bf16, 0 => fp32

  if (blockIdx.x == 8192) {  // flag + maskb producer
    if (tid == 0) flag[0] = isbf;
    if (isbf) {
#pragma unroll
      for (int i = 0; i < 2; i++)
        ((int4*)maskb)[tid * 2 + i] = ((const int4*)msrc)[tid * 2 + i];
    } else {
#pragma unroll
      for (int i = 0; i < 4; i++) {
        float4 v = ((const float4*)msrc)[tid * 4 + i];
        int o = tid * 16 + i * 4;
        maskb[o + 0] = __float2bfloat16(v.x);
        maskb[o + 1] = __float2bfloat16(v.y);
        maskb[o + 2] = __float2bfloat16(v.z);
        maskb[o + 3] = __float2bfloat16(v.w);
      }
    }
    return;
  }

  if (blockIdx.x < 4096) {  // x cvt (fp32 path only; bf16 path reads x directly)
    if (isbf) return;
    int i = (blockIdx.x * 256 + tid) * 4;
    float4 v = ((const float4*)xsrc)[i >> 2];
    xb[i + 0] = __float2bfloat16(v.x);
    xb[i + 1] = __float2bfloat16(v.y);
    xb[i + 2] = __float2bfloat16(v.z);
    xb[i + 3] = __float2bfloat16(v.w);
    return;
  }

  constexpr int R = 1024;
  const int t = blockIdx.x - 4096;
  const int bxi = t & 127;       // original transpose blockIdx.x
  const int by = (t >> 7) * 32;  // original blockIdx.y*32
  const void* in;
  bf16* out;
  int C, bx;
  if (bxi < 96) { in = in0; out = out0; C = 3072; bx = bxi * 32; }
  else          { in = in1; out = out1; C = 1024; bx = (bxi - 96) * 32; }
  int tx = tid & 31, ty = tid >> 5;
#pragma unroll
  for (int i = 0; i < 4; i++) {
    size_t idx = (size_t)(by + ty + i * 8) * C + bx + tx;
    tile[ty + i * 8][tx] =
        isbf ? ((const bf16*)in)[idx] : __float2bfloat16(((const float*)in)[idx]);
  }
  __syncthreads();
#pragma unroll
  for (int i = 0; i < 4; i++)
    out[(size_t)(bx + ty + i * 8) * R + by + tx] = tile[tx][ty + i * 8];
}

// ---------------- GEMM: C[M,N] = A[M,1024] @ Bt[N,1024]^T ----------------
// 128x128 tiles, BK=64 (two verbatim 128x32 halves per barrier pair -> half the
// vmcnt(0)-drain barriers of BK=32). LDS 32KB. __launch_bounds__(256,2).
// Tuning ledger: (256,3) VGPR cap -> neutral-negative (r12); NT=192 one-round
// grid -> -9us regression (r14, register pressure + longer inter-barrier path
// beat the tail saving). This 128x128/BK=64/(256,2) config is the measured
// optimum of the family.
// MODE 0: A = x [4096,1024], N=3072; scatters Q->[b,h,n,d], K and V in
// FRAGMENT-PACKED layouts (flash_k reads each MFMA fragment as one
// wave-contiguous 1KB load): packed elem (t=key>>6, half, c, gh, l31, j) at
// t*4096 + half*2048 + c*512 + gh*256 + l31*8 + j.
//   K: half=kt=(key>>5)&1, l31=key&31, d=(c*2+gh)*8+j  (pre-scaled KSCALE*mask)
//   V: half=dt=d>>5,       l31=d&31,   key_local=(c*2+gh)*8+j
// MODE 1: A = AO [4096,1024] (linear), N=1024 -> Co (bf16/f32 per flag).
// XCD-aware bijective swizzle (T1): nwg = 768 / 256, both % 8 == 0.
template <int MODE>
__global__ __launch_bounds__(256, 2)
void gemm_k(const bf16* __restrict__ A, const bf16* __restrict__ Aalt,
            const bf16* __restrict__ Bt,
            bf16* __restrict__ Qo, bf16* __restrict__ Ko, bf16* __restrict__ Vo,
            void* __restrict__ Co, const bf16* __restrict__ Mk,
            const int* __restrict__ flag) {
  constexpr int K = 1024;
  __shared__ __align__(16) bf16 As[128 * 64];  // two 128x32 halves (0 / +4096)
  __shared__ __align__(16) bf16 Bs[128 * 64];

  const int tid = threadIdx.x;
  const int lane = tid & 63;
  const int wv = tid >> 6;
  const int wm = wv & 1, wn = wv >> 1;
  const int l15 = lane & 15, quad = lane >> 4;

  const int nbx = gridDim.x;
  const int nwg = nbx * gridDim.y;
  int wid = blockIdx.y * nbx + blockIdx.x;
  wid = (wid & 7) * (nwg >> 3) + (wid >> 3);
  const int bm = (wid / nbx) * 128;
  const int bn = (wid % nbx) * 128;

  const int sml = tid >> 2;
  const int sg = (tid & 3) ^ ((sml >> 1) & 3);

  const int isbf = *flag;
  const bf16* Ab = (MODE == 0 && isbf) ? Aalt : A;

  floatx4 acc[4][4] = {};

  for (int k0 = 0; k0 < K; k0 += 64) {
    __syncthreads();
#pragma unroll
    for (int hf = 0; hf < 2; hf++) {
      const bf16* a0 = Ab + (size_t)(bm + sml) * K + k0 + hf * 32 + sg * 8;
      gload_lds16(a0, &As[hf * 4096 + tid * 8]);
      gload_lds16(a0 + (size_t)64 * K, &As[hf * 4096 + 2048 + tid * 8]);
      const bf16* b0 = Bt + (size_t)(bn + sml) * K + k0 + hf * 32 + sg * 8;
      gload_lds16(b0, &Bs[hf * 4096 + tid * 8]);
      gload_lds16(b0 + (size_t)64 * K, &Bs[hf * 4096 + 2048 + tid * 8]);
    }
    __syncthreads();

#pragma unroll
    for (int hf = 0; hf < 2; hf++) {
      const bf16* Ah = &As[hf * 4096];
      const bf16* Bh = &Bs[hf * 4096];
      short8 af[4], bfr[4];
#pragma unroll
      for (int mi = 0; mi < 4; mi++) {
        int m = wm * 64 + mi * 16 + l15;
        af[mi] = *(const short8*)&Ah[m * 32 + ((quad ^ ((m >> 1) & 3)) * 8)];
      }
#pragma unroll
      for (int ni = 0; ni < 4; ni++) {
        int n = wn * 64 + ni * 16 + l15;
        bfr[ni] = *(const short8*)&Bh[n * 32 + ((quad ^ ((n >> 1) & 3)) * 8)];
      }
#pragma unroll
      for (int mi = 0; mi < 4; mi++)
#pragma unroll
        for (int ni = 0; ni < 4; ni++)
          acc[mi][ni] = MFMA_BF16(af[mi], bfr[ni], acc[mi][ni]);
    }
  }

#pragma unroll
  for (int mi = 0; mi < 4; mi++) {
    const int row0 = bm + wm * 64 + mi * 16 + quad * 4;
#pragma unroll
    for (int ni = 0; ni < 4; ni++) {
      const int col = bn + wn * 64 + ni * 16 + l15;
      if (MODE == 0) {
        const int sec = col >> 10;
        const int cc = col & 1023;
        const int h = cc >> 6, d = cc & 63;
        const int b_idx = row0 >> 11;
        const int nn0 = row0 & 2047;
        if (sec == 0) {
          bf16* dst = Qo + (size_t)(b_idx * 16 + h) * 131072 + (size_t)nn0 * 64 + d;
#pragma unroll
          for (int r = 0; r < 4; r++) dst[r * 64] = __float2bfloat16(acc[mi][ni][r]);
        } else if (sec == 1) {
          // fold SCALE*log2e*mask_j into K rows; packed-fragment K layout.
          const bf16* mrow = Mk + (size_t)b_idx * 2048 + nn0;
          const int t = nn0 >> 6, kt = (nn0 >> 5) & 1, l31r = nn0 & 31;
          const int g = d >> 3, j = d & 7;
          bf16* dst = Ko + (size_t)(b_idx * 16 + h) * 131072 + t * 4096 + kt * 2048 +
                      (g >> 1) * 512 + (g & 1) * 256 + l31r * 8 + j;
#pragma unroll
          for (int r = 0; r < 4; r++)
            dst[r * 8] = __float2bfloat16(acc[mi][ni][r] * KSCALE *
                                          __bfloat162float(mrow[r]));
        } else {
          // packed-fragment V layout. key = nn0 + r: j = (nn0&7)+r.
          const int t = nn0 >> 6;
          const int kl = nn0 & 63;
          const int g = kl >> 3, j0 = kl & 7;
          bf16* dst = Vo + (size_t)(b_idx * 16 + h) * 131072 + t * 4096 +
                      (d >> 5) * 2048 + (g >> 1) * 512 + (g & 1) * 256 + (d & 31) * 8 + j0;
          ushort4 u;
          u.x = bfbits(acc[mi][ni][0]);
          u.y = bfbits(acc[mi][ni][1]);
          u.z = bfbits(acc[mi][ni][2]);
          u.w = bfbits(acc[mi][ni][3]);
          *(ushort4*)dst = u;
        }
      } else {
        if (isbf) {
          bf16* C2 = (bf16*)Co;
#pragma unroll
          for (int r = 0; r < 4; r++)
            C2[(size_t)(row0 + r) * 1024 + col] = __float2bfloat16(acc[mi][ni][r]);
        } else {
          float* C2 = (float*)Co;
#pragma unroll
          for (int r = 0; r < 4; r++)
            C2[(size_t)(row0 + r) * 1024 + col] = acc[mi][ni][r];
        }
      }
    }
  }
}

// ---------------- flash attention v15 (converged: ~48.4-50us) -------------------
// Accepted floor after 9 structural variants (48.3-56us across staging/
// pipelining/waves/stagger axes; latency-structure-bound at 4 waves/SIMD,
// MfmaUtil ~28% with nothing saturated). 4 waves/SIMD, direct-L2 fragment-
// packed KV (FETCH 12MB vs 70MB staged), KV-split halves, no main-loop
// barriers; exp2 to fresh scalars; deferred rsum (one shfl at end); T12
// in-register P->bf16 (cvt_pk + permlane32_swap); XCD swizzle.
__global__ __launch_bounds__(512, 4)
void flash_k(const bf16* __restrict__ Q, const bf16* __restrict__ Kp,
             const bf16* __restrict__ Vp, bf16* __restrict__ AO) {
  __shared__ __align__(16) float cb[4 * 64 * 32];  // 32 KB combine buffer
  __shared__ float rbuf[4 * 64];                   // 1 KB rsum combine

  const int tid = threadIdx.x;
  const int lane = tid & 63;
  const int l31 = lane & 31;
  const int l5h = lane >> 5;  // 0..1
  const int w = tid >> 6;     // 0..7
  const int rg = w & 3;       // row group (32 rows each)
  const int half = w >> 2;    // KV half: 0 -> keys 0..1023, 1 -> 1024..2047

  // XCD-aware swizzle (bijective, 512 % 8 == 0)
  const int bid = blockIdx.x;
  const int wk = (bid & 7) * 64 + (bid >> 3);
  const int qt = wk & 15;  // 16 tiles x 128 rows
  const int hl = wk >> 4;  // b*16+h
  const int b_idx = hl >> 4, h = hl & 15;

  const bf16* Qh = Q + (size_t)hl * 131072;
  const int lo = l5h * 256 + l31 * 8;  // per-lane elem offset inside a fragment
  const bf16* kptr = Kp + (size_t)hl * 131072 + (size_t)(half * 16) * 4096 + lo;
  const bf16* vptr = Vp + (size_t)hl * 131072 + (size_t)(half * 16) * 4096 + lo;

  const int qbase = qt * 128 + rg * 32;
  const int qrow = qbase + l31;

  // Q fragments (B-operand of S^T): B[k=d][n=row]: lane n=l31, k=c*16+l5h*8+j
  short8 qf[4];
#pragma unroll
  for (int c = 0; c < 4; c++)
    qf[c] = *(const short8*)&Qh[(size_t)qrow * 64 + c * 16 + l5h * 8];

  floatx16 o_acc[2] = {};  // O^T: col=l31=row, d = dt*32 + (reg&3)+8*(reg>>2)+4*l5h
  float rsm0 = 0.f, rsm1 = 0.f, rsm2 = 0.f, rsm3 = 0.f;  // lane-local partials

  // preload K fragments of 32-key tile 0 (K packed: 32-key subtile stride 2048)
  short8 kf[4];
#pragma unroll
  for (int c = 0; c < 4; c++) kf[c] = *(const short8*)(kptr + c * 512);

#pragma unroll 1
  for (int it = 0; it < 32; ++it) {
    const int kv = it & 1;  // which 32-key half of the 64-key packed tile

    // S^T = K' Q^T : A = K'[key][d]: lane row=key=l31, k=l5h*8+j per c-chunk
    floatx16 s = {};
    __builtin_amdgcn_s_setprio(1);
#pragma unroll
    for (int c = 0; c < 4; c++) s = MFMA32(kf[c], qf[c], s);
    __builtin_amdgcn_s_setprio(0);

    // V loads for this tile, issued FIRST (in-order vmcnt => PV's wait doesn't
    // drain the K prefetch behind them)
    short8 vf[4];
#pragma unroll
    for (int dt = 0; dt < 2; dt++)
#pragma unroll
      for (int ch = 0; ch < 2; ch++)
        vf[dt * 2 + ch] = *(const short8*)(vptr + dt * 2048 + (kv * 2 + ch) * 512);

    // prefetch K fragments of next tile (kf dead after S-MFMAs)
    kptr += (it < 31) ? 2048 : 0;
#pragma unroll
    for (int c = 0; c < 4; c++) kf[c] = *(const short8*)(kptr + c * 512);

    // p = exp2(s) into FRESH scalars (no write-back into the AGPR-resident s)
    float e[16];
#pragma unroll
    for (int r = 0; r < 16; r += 4) {
      e[r + 0] = __builtin_amdgcn_exp2f(s[r + 0]);
      e[r + 1] = __builtin_amdgcn_exp2f(s[r + 1]);
      e[r + 2] = __builtin_amdgcn_exp2f(s[r + 2]);
      e[r + 3] = __builtin_amdgcn_exp2f(s[r + 3]);
      rsm0 += e[r + 0];
      rsm1 += e[r + 1];
      rsm2 += e[r + 2];
      rsm3 += e[r + 3];
    }

    // pf[ch][j] = P[key=ch*16+l5h*8+j][row=l31], built in-register (T12).
    short8 pf[2];
#pragma unroll
    for (int ch = 0; ch < 2; ch++) {
      const int rb = ch * 8;
      unsigned x0, x1, y0, y1;
      asm("v_cvt_pk_bf16_f32 %0, %1, %2" : "=v"(x0) : "v"(e[rb + 0]), "v"(e[rb + 1]));
      asm("v_cvt_pk_bf16_f32 %0, %1, %2" : "=v"(x1) : "v"(e[rb + 2]), "v"(e[rb + 3]));
      asm("v_cvt_pk_bf16_f32 %0, %1, %2" : "=v"(y0) : "v"(e[rb + 4]), "v"(e[rb + 5]));
      asm("v_cvt_pk_bf16_f32 %0, %1, %2" : "=v"(y1) : "v"(e[rb + 6]), "v"(e[rb + 7]));
      asm("v_permlane32_swap_b32 %0, %1" : "+v"(x0), "+v"(y0));
      asm("v_permlane32_swap_b32 %0, %1" : "+v"(x1), "+v"(y1));
      union { unsigned u[4]; short8 v; } cv;
      cv.u[0] = x0; cv.u[1] = x1; cv.u[2] = y0; cv.u[3] = y1;
      pf[ch] = cv.v;
    }

    // O^T += V^T P^T : A = V^T[d][key]: lane row=d=dt*32+l31 (per dt)
    __builtin_amdgcn_s_setprio(1);
#pragma unroll
    for (int dt = 0; dt < 2; dt++)
#pragma unroll
      for (int ch = 0; ch < 2; ch++)
        o_acc[dt] = MFMA32(vf[dt * 2 + ch], pf[ch], o_acc[dt]);
    __builtin_amdgcn_s_setprio(0);

    vptr += kv ? 4096 : 0;  // V packed-tile (64-key) stride, advance every 2 iters
  }

  // deferred rsum: one cross-half-of-wave shfl for this wave's 1024 keys
  float rsum = (rsm0 + rsm1) + (rsm2 + rsm3);
  rsum += __shfl_xor(rsum, 32, 64);

  // ---- combine KV halves: waves 4-7 hand o_acc/rsum to partner via LDS ----
  if (w >= 4) {
    const int slot = (w - 4) * 64 + lane;
    float4* dst = (float4*)(cb + (size_t)slot * 32);
#pragma unroll
    for (int dt = 0; dt < 2; dt++)
#pragma unroll
      for (int q = 0; q < 4; q++) {
        float4 v = make_float4(o_acc[dt][q * 4 + 0], o_acc[dt][q * 4 + 1],
                               o_acc[dt][q * 4 + 2], o_acc[dt][q * 4 + 3]);
        dst[(dt * 4 + q) ^ (lane & 7)] = v;  // xor-swizzle: conflict-free
      }
    rbuf[slot] = rsum;
  }
  __syncthreads();
  if (w < 4) {
    const int slot = w * 64 + lane;
    const float4* src = (const float4*)(cb + (size_t)slot * 32);
#pragma unroll
    for (int dt = 0; dt < 2; dt++)
#pragma unroll
      for (int q = 0; q < 4; q++) {
        float4 v = src[(dt * 4 + q) ^ (lane & 7)];
        o_acc[dt][q * 4 + 0] += v.x;
        o_acc[dt][q * 4 + 1] += v.y;
        o_acc[dt][q * 4 + 2] += v.z;
        o_acc[dt][q * 4 + 3] += v.w;
      }
    rsum += rbuf[slot];

    // epilogue: lane owns q-row qbase+l31; AO linear [b*2048+n][1024], col=h*64+d
    const float rinv = 1.f / rsum;
    bf16* orow = AO + (size_t)(b_idx * 2048 + qbase + l31) * 1024 + h * 64;
#pragma unroll
    for (int dt = 0; dt < 2; dt++)
#pragma unroll
      for (int rg2 = 0; rg2 < 4; rg2++) {
        ushort4 u;
        u.x = bfbits(o_acc[dt][rg2 * 4 + 0] * rinv);
        u.y = bfbits(o_acc[dt][rg2 * 4 + 1] * rinv);
        u.z = bfbits(o_acc[dt][rg2 * 4 + 2] * rinv);
        u.w = bfbits(o_acc[dt][rg2 * 4 + 3] * rinv);
        *(ushort4*)&orow[dt * 32 + rg2 * 8 + l5h * 4] = u;
      }
  }
}

extern "C" void kernel_launch(void* const* d_in, const int* in_sizes, int n_in,
                              void* d_out, int out_size, void* d_ws, size_t ws_size,
                              hipStream_t stream) {
  const void* x     = d_in[0];  // [2,2048,1024]  bf16 or fp32 (probed)
  const void* mask  = d_in[1];  // [2,2048]
  const void* w_qkv = d_in[2];  // [1024,3072]
  const void* w_out = d_in[3];  // [1024,1024]

  bf16* ws    = (bf16*)d_ws;
  bf16* xb    = ws;                     // 4194304 (fp32 path only; dead after gemm1)
  bf16* AO    = ws;                     // alias of xb, linear [4096,1024]
  bf16* wqkvT = ws + 4194304;           // 3145728
  bf16* woutT = wqkvT + 3145728;        // 1048576
  bf16* Qb    = woutT + 1048576;        // 4194304
  bf16* Kp    = Qb + 4194304;           // 4194304 (fragment-packed K)
  bf16* maskb = Kp + 4194304;           // 4096
  int*  flag  = (int*)(maskb + 4096);
  bf16* Vp    = (bf16*)d_out;           // 4194304 packed V (dead before gemm2 writes)

  prep_k<<<8193, 256, 0, stream>>>(mask, maskb, flag, x, xb, w_qkv, wqkvT,
                                   w_out, woutT);
  gemm_k<0><<<dim3(24, 32), 256, 0, stream>>>(xb, (const bf16*)x, wqkvT, Qb, Kp, Vp,
                                              nullptr, maskb, flag);
  flash_k<<<512, 512, 0, stream>>>(Qb, Kp, Vp, AO);
  gemm_k<1><<<dim3(8, 32), 256, 0, stream>>>(AO, nullptr, woutT, nullptr, nullptr,
                                             nullptr, d_out, nullptr, flag);
}